// Round 6
// baseline (191.008 us; speedup 1.0000x reference)
//
#include <hip/hip_runtime.h>
#include <math.h>

#define IN_DIM  512
#define OUT_DIM 512
#define BATCH   2
#define NPTS    50000
#define TOTAL   (BATCH * NPTS)

#define NBLK    1024                 // 4 waves/blk -> 4096 waves; <= 4 blk/CU co-resident guaranteed
#define NWAVE   (NBLK * 4)
#define NPROD   (BATCH * IN_DIM)     // 1024 producer waves, one per (b,d)

typedef float f4 __attribute__((ext_vector_type(4)));

__device__ __forceinline__ float dot8(f4 a0, f4 a1, f4 b0, f4 b1) {
    return a0[0]*b0[0] + a0[1]*b0[1] + a0[2]*b0[2] + a0[3]*b0[3]
         + a1[0]*b1[0] + a1[1]*b1[1] + a1[2]*b1[2] + a1[3]*b1[3];
}

__device__ __forceinline__ float wred(float x) {
    #pragma unroll
    for (int off = 32; off; off >>= 1) x += __shfl_xor(x, off);
    return x;
}

// Fused: producer waves (first 1024) compute v = mat @ s[b] and count into
// flag; ALL waves prefetch their first z-pair before spinning, so the HBM
// pipe is busy during the producer phase. Consumers then stream 2 rows per
// grid-stride step (R1 measured-best structure).
__global__ __launch_bounds__(256, 4) void dgi_fused(
    const float* __restrict__ z, const float* __restrict__ s,
    const float* __restrict__ mat, float* __restrict__ out,
    float* __restrict__ v, unsigned int* __restrict__ flag)
{
    const int lane = threadIdx.x & 63;
    const int wid  = (int)((blockIdx.x * blockDim.x + threadIdx.x) >> 6);

    // ---- producer phase (waves 0..1023): v[b][d] = mat[d,:] . s[b,:] ----
    if (wid < NPROD) {
        const int b = wid >> 9;
        const int d = wid & 511;
        const f4* mrow = reinterpret_cast<const f4*>(mat + (size_t)d * OUT_DIM);
        const f4* srow = reinterpret_cast<const f4*>(s   + (size_t)b * OUT_DIM);
        const f4 m0 = mrow[lane], m1 = mrow[lane + 64];
        const f4 w0 = srow[lane], w1 = srow[lane + 64];
        const float acc = wred(dot8(m0, m1, w0, w1));
        if (lane == 0) {
            v[b * IN_DIM + d] = acc;
            __threadfence();   // make v visible device-wide before counting
            __hip_atomic_fetch_add(flag, 1u, __ATOMIC_RELAXED,
                                   __HIP_MEMORY_SCOPE_AGENT);
        }
    }

    // ---- prefetch first pair (rows 2*wid, 2*wid+1 -> always batch 0) ----
    const long r0 = (long)wid * 2;
    const f4* zA = reinterpret_cast<const f4*>(z + r0 * IN_DIM);
    const f4* zB = reinterpret_cast<const f4*>(z + (r0 + 1) * IN_DIM);
    const f4 pa0 = zA[lane], pa1 = zA[lane + 64];
    const f4 pb0 = zB[lane], pb1 = zB[lane + 64];

    // ---- wait for v (relaxed spin; acquire via fence after) ----
    while (__hip_atomic_load(flag, __ATOMIC_RELAXED,
                             __HIP_MEMORY_SCOPE_AGENT) < NPROD)
        __builtin_amdgcn_s_sleep(4);
    __threadfence();

    const f4* vr = reinterpret_cast<const f4*>(v);   // batch 0
    f4 v0 = vr[lane], v1 = vr[lane + 64];
    int b_cur = 0;

    // first (prefetched) pair
    {
        const float rA = wred(dot8(pa0, pa1, v0, v1));
        const float rB = wred(dot8(pb0, pb1, v0, v1));
        if (lane == 0) {
            out[r0]     = 1.0f / (1.0f + __expf(-rA));
            out[r0 + 1] = 1.0f / (1.0f + __expf(-rB));
        }
    }

    // remaining pairs, grid-stride; pairs are even-aligned so a pair never
    // straddles the batch boundary (NPTS even)
    for (long r = r0 + 2 * NWAVE; r < TOTAL; r += 2 * NWAVE) {
        const f4* zC = reinterpret_cast<const f4*>(z + r * IN_DIM);
        const f4* zD = reinterpret_cast<const f4*>(z + (r + 1) * IN_DIM);
        const f4 a0 = zC[lane], a1 = zC[lane + 64];
        const f4 c0 = zD[lane], c1 = zD[lane + 64];

        const int b = (r >= NPTS);
        if (b != b_cur) {
            b_cur = b;
            const f4* vb = reinterpret_cast<const f4*>(v + (size_t)b * IN_DIM);
            v0 = vb[lane]; v1 = vb[lane + 64];
        }
        const float rA = wred(dot8(a0, a1, v0, v1));
        const float rB = wred(dot8(c0, c1, v0, v1));
        if (lane == 0) {
            out[r]     = 1.0f / (1.0f + __expf(-rA));
            out[r + 1] = 1.0f / (1.0f + __expf(-rB));
        }
    }
}

extern "C" void kernel_launch(void* const* d_in, const int* in_sizes, int n_in,
                              void* d_out, int out_size, void* d_ws, size_t ws_size,
                              hipStream_t stream) {
    const float* z   = (const float*)d_in[0];   // [2, 50000, 512] f32
    const float* s   = (const float*)d_in[1];   // [2, 512] f32
    const float* mat = (const float*)d_in[2];   // [512, 512] f32
    float* out = (float*)d_out;                 // [2, 50000] f32

    float*        v    = (float*)d_ws;                          // 4 KB
    unsigned int* flag = (unsigned int*)((char*)d_ws + 4096);   // 4 B

    // flag must be 0 at kernel start on every call (d_ws is poisoned once
    // and never re-poisoned; deterministic reset, graph-capture legal)
    hipMemsetAsync(flag, 0, sizeof(unsigned int), stream);

    dgi_fused<<<NBLK, 256, 0, stream>>>(z, s, mat, out, v, flag);
}

// Round 7
// 38.483 us; speedup vs baseline: 4.9635x; 4.9635x over previous
//
#include <hip/hip_runtime.h>
#include <math.h>

#define IN_DIM  512
#define OUT_DIM 512
#define BATCH   2
#define NPTS    50000
#define TOTAL   (BATCH * NPTS)
#define RPW     4                        // rows per wave; 100000/4 = 25000 waves exact
#define NWAVES  (TOTAL / RPW)            // 25000
#define NBLK    (NWAVES / 4)             // 6250 blocks x 4 waves

typedef float f4 __attribute__((ext_vector_type(4)));

__device__ __forceinline__ float dot8(f4 a0, f4 a1, f4 b0, f4 b1) {
    return a0[0]*b0[0] + a0[1]*b0[1] + a0[2]*b0[2] + a0[3]*b0[3]
         + a1[0]*b1[0] + a1[1]*b1[1] + a1[2]*b1[2] + a1[3]*b1[3];
}

__device__ __forceinline__ float wred(float x) {
    #pragma unroll
    for (int off = 32; off; off >>= 1) x += __shfl_xor(x, off);
    return x;   // full sum in ALL lanes
}

__device__ __forceinline__ float sigmoidf(float x) {
    return 1.0f / (1.0f + __expf(-x));
}

// Kernel 1: v[b][d] = sum_e mat[d][e] * s[b][e]   (v: [2][512] f32 in d_ws)
// 1024 waves, one per (b,d). s is 4 KB -> L2-resident, mat rows coalesced f4.
__global__ __launch_bounds__(256) void dgi_compute_v(
    const float* __restrict__ mat, const float* __restrict__ s,
    float* __restrict__ v)
{
    const int lane = threadIdx.x & 63;
    const int W    = (int)((blockIdx.x * blockDim.x + threadIdx.x) >> 6);
    const int b    = W >> 9;
    const int d    = W & 511;

    const f4* mrow = reinterpret_cast<const f4*>(mat + (size_t)d * OUT_DIM);
    const f4* srow = reinterpret_cast<const f4*>(s   + (size_t)b * OUT_DIM);
    const f4 m0 = mrow[lane], m1 = mrow[lane + 64];
    const f4 s0 = srow[lane], s1 = srow[lane + 64];

    float acc = wred(dot8(m0, m1, s0, s1));
    if (lane == 0) v[b * IN_DIM + d] = acc;
}

// Kernel 2: out[row] = sigmoid( z[row,:] . v[b,:] ), b = row >= NPTS.
// Fill-kernel-style: 25000 identical SHORT waves, each exactly 4 contiguous
// rows (8 KB), no loop. 8 independent float4 loads in flight, 4 parallel
// reduce chains, one packed 16B store. Dynamic block scheduling balances;
// no fixed large stride between streams (no L2 set aliasing); no remainder,
// no batch straddle (50000 % 4 == 0).
__global__ __launch_bounds__(256) void dgi_score(
    const float* __restrict__ z, const float* __restrict__ v,
    float* __restrict__ out)
{
    const int lane = threadIdx.x & 63;
    const int wid  = (int)((blockIdx.x * blockDim.x + threadIdx.x) >> 6);

    const long r0 = (long)wid * RPW;         // 4 contiguous rows, one batch
    const int  b  = (r0 >= NPTS);

    const f4* vr = reinterpret_cast<const f4*>(v + (size_t)b * IN_DIM);
    const f4 v0 = vr[lane], v1 = vr[lane + 64];

    const f4* zp = reinterpret_cast<const f4*>(z + r0 * IN_DIM);  // row = 128 f4
    const f4 a0 = zp[lane],       a1 = zp[lane + 64];
    const f4 b0 = zp[lane + 128], b1 = zp[lane + 192];
    const f4 c0 = zp[lane + 256], c1 = zp[lane + 320];
    const f4 d0 = zp[lane + 384], d1 = zp[lane + 448];

    const float rA = wred(dot8(a0, a1, v0, v1));
    const float rB = wred(dot8(b0, b1, v0, v1));
    const float rC = wred(dot8(c0, c1, v0, v1));
    const float rD = wred(dot8(d0, d1, v0, v1));

    // packed epilogue: lanes 0-3 store the 4 results (one 16B-wide store)
    const float r = (lane == 0) ? rA : (lane == 1) ? rB : (lane == 2) ? rC : rD;
    if (lane < 4) out[r0 + lane] = sigmoidf(r);
}

extern "C" void kernel_launch(void* const* d_in, const int* in_sizes, int n_in,
                              void* d_out, int out_size, void* d_ws, size_t ws_size,
                              hipStream_t stream) {
    const float* z   = (const float*)d_in[0];   // [2, 50000, 512] f32
    const float* s   = (const float*)d_in[1];   // [2, 512] f32
    const float* mat = (const float*)d_in[2];   // [512, 512] f32
    float* out = (float*)d_out;                 // [2, 50000] f32
    float* v   = (float*)d_ws;                  // [2, 512] f32 scratch

    dgi_compute_v<<<BATCH * 128, 256, 0, stream>>>(mat, s, v);
    dgi_score<<<NBLK, 256, 0, stream>>>(z, v, out);
}